// Round 9
// baseline (414.553 us; speedup 1.0000x reference)
//
#include <hip/hip_runtime.h>
#include <cstdint>
#include <cstddef>

typedef __bf16 bf16x8 __attribute__((ext_vector_type(8)));
typedef float f32x4 __attribute__((ext_vector_type(4)));
typedef float f32x16 __attribute__((ext_vector_type(16)));

#define SEQ   4096
#define HID   1280
#define NH    16
#define HD    80

__device__ __forceinline__ unsigned short f2bf(float f) {
  unsigned int u = __float_as_uint(f);
  unsigned int r = u + 0x7FFFu + ((u >> 16) & 1u);   // RNE
  return (unsigned short)(r >> 16);
}
__device__ __forceinline__ float bf2f(unsigned short h) {
  return __uint_as_float(((unsigned int)h) << 16);
}
__device__ __forceinline__ __bf16 us2bf(unsigned short u) {
  union { unsigned short s; __bf16 b; } c; c.s = u; return c.b;
}
__device__ __forceinline__ void dma16(const void* g, void* l) {
  __builtin_amdgcn_global_load_lds((const __attribute__((address_space(1))) unsigned int*)g,
                                   (__attribute__((address_space(3))) unsigned int*)l, 16, 0, 0);
}
__device__ __forceinline__ unsigned int cvtpk(float a, float b) {
  unsigned int w;
  asm("v_cvt_pk_bf16_f32 %0, %1, %2" : "=v"(w) : "v"(a), "v"(b));
  return w;
}
__device__ __forceinline__ float lo2f(unsigned int w) { return __uint_as_float(w << 16); }
__device__ __forceinline__ float hi2f(unsigned int w) { return __uint_as_float(w & 0xffff0000u); }

// ---------------- split: f32 -> bf16 hi only ---------------------------------
__global__ __launch_bounds__(256) void split_hi_kernel(const float* __restrict__ x,
                                                       unsigned short* __restrict__ hi,
                                                       int n4) {
  int i = blockIdx.x * 256 + threadIdx.x;
  if (i >= n4) return;
  float4 v = *((const float4*)x + i);
  *((ushort4*)hi + i) = make_ushort4(f2bf(v.x), f2bf(v.y), f2bf(v.z), f2bf(v.w));
}

// ---------------- transpose + split weights (hi/lo) --------------------------
__global__ __launch_bounds__(256) void tsplit_kernel(const float* __restrict__ W,
                                                     unsigned short* __restrict__ Thi,
                                                     unsigned short* __restrict__ Tlo,
                                                     int K, int N) {
  __shared__ float tile[32][33];
  int n0 = blockIdx.x * 32, k0 = blockIdx.y * 32;
  int tx = threadIdx.x & 31, ty = threadIdx.x >> 5;
#pragma unroll
  for (int i = 0; i < 32; i += 8)
    tile[ty + i][tx] = W[(size_t)(k0 + ty + i) * N + n0 + tx];
  __syncthreads();
#pragma unroll
  for (int i = 0; i < 32; i += 8) {
    float v = tile[tx][ty + i];
    size_t idx = (size_t)(n0 + ty + i) * K + (size_t)(k0 + tx);
    unsigned short h = f2bf(v);
    Thi[idx] = h;
    Tlo[idx] = f2bf(v - bf2f(h));
  }
}

// ---------------- 128x128 DMA GEMM, 2-term (A bf16, B hi/lo) -----------------
__global__ __launch_bounds__(256, 3) void gemm128_x2(
    const unsigned short* __restrict__ A, const unsigned short* __restrict__ Bh,
    const unsigned short* __restrict__ Bl, const float* __restrict__ bias,
    float* __restrict__ out0, float* __restrict__ out1, float* __restrict__ out2,
    int M, int N, int K) {
  __shared__ __align__(16) unsigned short sALL[3 * 8192];  // [A | Bh | Bl]

  const int t = threadIdx.x;
  const int lane = t & 63, wave = t >> 6;
  const int c16 = lane & 15, quad = lane >> 4;
  const int bm = blockIdx.y * 128, bn = blockIdx.x * 128;
  const int wr = (wave >> 1) * 64, wc = (wave & 1) * 64;
  const int lrow = lane >> 3;
  const int lswz = (lane & 7) ^ lrow;

  f32x4 acc[4][4];
#pragma unroll
  for (int i = 0; i < 4; ++i)
#pragma unroll
    for (int j = 0; j < 4; ++j) acc[i][j] = (f32x4){0.f, 0.f, 0.f, 0.f};

  const unsigned short* gp[12];
#pragma unroll
  for (int i = 0; i < 12; ++i) {
    const int ua = wave * 12 + i;
    const int arr = ua >> 4, sub = ua & 15;
    const unsigned short* g = (arr == 0) ? A : (arr == 1) ? Bh : Bl;
    const int rowg = ((arr == 0) ? bm : bn) + sub * 8 + lrow;
    gp[i] = g + (size_t)rowg * K + lswz * 8;
  }

  for (int k0 = 0; k0 < K; k0 += 64) {
    __syncthreads();
#pragma unroll
    for (int i = 0; i < 12; ++i)
      dma16(gp[i] + k0, &sALL[(wave * 12 + i) * 512]);
    __syncthreads();
#pragma unroll
    for (int ks = 0; ks < 2; ++ks) {
      bf16x8 a[4], bh[4], bl[4];
#pragma unroll
      for (int mi = 0; mi < 4; ++mi) {
        const int row = wr + mi * 16 + c16;
        const int off = row * 64 + (((ks * 4 + quad) ^ (row & 7)) * 8);
        a[mi] = *(const bf16x8*)&sALL[off];
      }
#pragma unroll
      for (int ni = 0; ni < 4; ++ni) {
        const int row = wc + ni * 16 + c16;
        const int off = row * 64 + (((ks * 4 + quad) ^ (row & 7)) * 8);
        bh[ni] = *(const bf16x8*)&sALL[8192 + off];
        bl[ni] = *(const bf16x8*)&sALL[16384 + off];
      }
#pragma unroll
      for (int mi = 0; mi < 4; ++mi)
#pragma unroll
        for (int ni = 0; ni < 4; ++ni) {
          acc[mi][ni] = __builtin_amdgcn_mfma_f32_16x16x32_bf16(a[mi], bh[ni], acc[mi][ni], 0, 0, 0);
          acc[mi][ni] = __builtin_amdgcn_mfma_f32_16x16x32_bf16(a[mi], bl[ni], acc[mi][ni], 0, 0, 0);
        }
    }
  }
#pragma unroll
  for (int ni = 0; ni < 4; ++ni) {
    int colg = bn + wc + ni * 16 + c16;
    float bv = bias[colg];
    float* op;
    int c = colg;
    if (c < 1280) op = out0;
    else if (c < 2560) { op = out1; c -= 1280; }
    else { op = out2; c -= 2560; }
#pragma unroll
    for (int mi = 0; mi < 4; ++mi)
#pragma unroll
      for (int r = 0; r < 4; ++r) {
        int rowg = bm + wr + mi * 16 + quad * 4 + r;
        op[(size_t)rowg * 1280 + c] = acc[mi][ni][r] + bv;
      }
  }
}

// ---------------- RoPE on q (in place, f32) + k -> packed bf16 hi/lo ---------
__global__ __launch_bounds__(256) void rope_pack_kernel(
    float* __restrict__ qf, const float* __restrict__ kf,
    const float* __restrict__ cs, const float* __restrict__ sn,
    unsigned short* __restrict__ khi, unsigned short* __restrict__ klo) {
  const int h = blockIdx.y;
  const int s = blockIdx.x * 64 + (threadIdx.x >> 2);
  const int p = threadIdx.x & 3;
  float* qrow = qf + (size_t)s * HID + h * HD;
  const float* krow = kf + (size_t)s * HID + h * HD;
  const float* cr = cs + (size_t)s * HD;
  const float* sr = sn + (size_t)s * HD;
  unsigned short* kh = khi + ((size_t)h * SEQ + s) * HD;
  unsigned short* kl = klo + ((size_t)h * SEQ + s) * HD;
#pragma unroll
  for (int j = 0; j < 10; ++j) {
    int d = 10 * p + j;           // 0..39
    float c0 = cr[d], s0 = sr[d], c1 = cr[d + 40], s1 = sr[d + 40];
    float q0 = qrow[d], q1 = qrow[d + 40];
    qrow[d]      = q0 * c0 - q1 * s0;
    qrow[d + 40] = q1 * c1 + q0 * s1;
    float k0 = krow[d], k1 = krow[d + 40];
    float kn0 = k0 * c0 - k1 * s0;
    float kn1 = k1 * c1 + k0 * s1;
    unsigned short h0 = f2bf(kn0), h1 = f2bf(kn1);
    kh[d] = h0;      kl[d] = f2bf(kn0 - bf2f(h0));
    kh[d + 40] = h1; kl[d + 40] = f2bf(kn1 - bf2f(h1));
  }
}

// ---------------- pack V^T: f32 [s][1280] -> bf16 hi/lo [h][80][4096] --------
__global__ __launch_bounds__(256) void vt_pack_kernel(const float* __restrict__ vf,
                                                      unsigned short* __restrict__ vthi,
                                                      unsigned short* __restrict__ vtlo) {
  __shared__ unsigned short sTh[80][72];
  __shared__ unsigned short sTl[80][72];
  const int h = blockIdx.y;
  const int s0 = blockIdx.x * 64;
  const int t = threadIdx.x;
  {
    int row = t >> 2, p = (t & 3) * 20;
    const float* src = vf + (size_t)(s0 + row) * HID + h * HD + p;
#pragma unroll
    for (int i = 0; i < 5; ++i) {
      float4 v = *(const float4*)(src + 4 * i);
      float vv[4] = {v.x, v.y, v.z, v.w};
#pragma unroll
      for (int j = 0; j < 4; ++j) {
        int d = p + 4 * i + j;
        unsigned short hu = f2bf(vv[j]);
        sTh[d][row] = hu;
        sTl[d][row] = f2bf(vv[j] - bf2f(hu));
      }
    }
  }
  __syncthreads();
  if (t < 160) {
    int d = t >> 1, half = (t & 1) * 32;
    size_t base = (size_t)(h * HD + d) * SEQ + s0 + half;
#pragma unroll
    for (int i = 0; i < 8; ++i) {
      *(ushort4*)&vthi[base + 4 * i] = *(ushort4*)&sTh[d][half + 4 * i];
      *(ushort4*)&vtlo[base + 4 * i] = *(ushort4*)&sTl[d][half + 4 * i];
    }
  }
}

// ---------------- scheduler: 8 per-XCD LPT queues of 256 units ---------------
__global__ __launch_bounds__(128) void sched_kernel(const int* __restrict__ cu,
                                                    int* __restrict__ perm,
                                                    unsigned int* __restrict__ ctr) {
  __shared__ int w[128];
  const int t = threadIdx.x;
  if (t < 8) ctr[t * 16] = 0u;   // 8 counters, 64B apart
  int cu_r[9];
#pragma unroll
  for (int i = 0; i < 9; ++i) cu_r[i] = cu[i];
  const int r0 = t * 32;
  int sg0 = 0, sg1 = 0;
#pragma unroll
  for (int i = 1; i < 8; ++i) {
    sg0 += (r0      >= cu_r[i]) ? 1 : 0;
    sg1 += (r0 + 31 >= cu_r[i]) ? 1 : 0;
  }
  const int ck0 = cu_r[sg0] & ~31;
  const int kend = cu_r[sg1 + 1];
  w[t] = (kend - ck0 + 31) >> 5;
  __syncthreads();
  const int wt = w[t];
  int rank = 0;
  for (int i = 0; i < 128; ++i)
    rank += ((w[i] > wt) || (w[i] == wt && i < t)) ? 1 : 0;
#pragma unroll
  for (int x = 0; x < 8; ++x) {
    perm[x * 256 + rank * 2 + 0] = (2 * x) * 128 + t;
    perm[x * 256 + rank * 2 + 1] = (2 * x + 1) * 128 + t;
  }
}

// ---------------- attention: wave-autonomous workers, V in registers ---------
// 1024 blocks x 128 thr (4 blocks/CU, 8 waves/CU all with work). Block b pulls
// from queue b&7 (256 units/XCD = 256 wave slots -> one unit per wave, LPT
// spread). Per wave: 32 queries, K hi/lo staged in 10KB private LDS
// (sigma-permuted, conflict-free); V^T read DIRECTLY into registers from
// global (L2-resident under XCD locality) - no V LDS, no manual pre-PV wait.
// vmcnt FIFO: V reg-loads issued BEFORE K(i+1) dma batch, so compiler's
// auto-waits for PV resolve at vmcnt(10), leaving K prefetch in flight.
// Manual loop-top vmcnt(0) drains K(ci) (issued a full chunk earlier).

#define MFMA32(A, B, C) __builtin_amdgcn_mfma_f32_32x32x16_bf16(A, B, C, 0, 0, 0)

__global__ __launch_bounds__(128, 2) void attn_kernel(
    const float* __restrict__ qf, const unsigned short* __restrict__ khi,
    const unsigned short* __restrict__ klo, const unsigned short* __restrict__ vthi,
    const unsigned short* __restrict__ vtlo, const int* __restrict__ cu,
    unsigned short* __restrict__ ohi, const int* __restrict__ perm,
    unsigned int* __restrict__ ctr) {
  __shared__ __align__(16) unsigned short sAll[10240];   // 20480 B = 2 x 10KB waves

  const int t = threadIdx.x;
  const int lane = t & 63, wave = t >> 6;
  const int ln5 = lane & 31;                    // query col / frag row
  const int hi  = lane >> 5;                    // k-half
  const int ln7 = lane & 7;
  const int xcd = blockIdx.x & 7;

  unsigned short* const wb  = sAll + wave * 5120;   // wave-private 10KB
  unsigned short* const sKh = wb;                   // [32 key][80 d] sigma
  unsigned short* const sKl = wb + 2560;

  int cu_r[9];
#pragma unroll
  for (int i = 0; i < 9; ++i) cu_r[i] = cu[i];

  // K DMA source offsets: granule G = i*64+lane -> key=G/10, pos=G%10,
  // src col = pos^(key&7) for pos<8 else pos  (involution)
  int koff[5];
#pragma unroll
  for (int i = 0; i < 5; ++i) {
    const int G = i * 64 + lane;
    const int key = (G * 205) >> 11;            // exact /10 for G<1024
    const int p = G - key * 10;
    const int cl = (p < 8) ? (p ^ (key & 7)) : p;
    koff[i] = key * 80 + cl * 8;
  }
  // K read columns (shorts) per kd
  int ccol[5];
#pragma unroll
  for (int c = 0; c < 5; ++c)
    ccol[c] = (c < 4) ? ((((2 * c) + hi) ^ ln7) * 8) : ((8 + hi) * 8);

  // V^T register-fragment rows (A-operand rows = output dims)
  const size_t vra = (size_t)ln5 * SEQ;
  const size_t vrb = (size_t)(32 + ln5) * SEQ;
  const size_t vrc = (size_t)(64 + (ln5 & 15)) * SEQ;

  const float qsc = 0.11180339887498949f * 1.4426950408889634f;  // *log2(e)

  for (;;) {
    unsigned int idx = 0;
    if (lane == 0) idx = atomicAdd(&ctr[xcd * 16], 1u);
    idx = (unsigned int)__shfl((int)idx, 0);
    if (idx >= 256u) break;
    const int uu = perm[xcd * 256 + idx];
    const int h = uu >> 7;
    const int r0 = (uu & 127) * 32;

    const int q_my = r0 + ln5;
    int sq = 0, sg0 = 0, sg1 = 0;
#pragma unroll
    for (int i = 1; i < 8; ++i) {
      sq  += (q_my    >= cu_r[i]) ? 1 : 0;
      sg0 += (r0      >= cu_r[i]) ? 1 : 0;
      sg1 += (r0 + 31 >= cu_r[i]) ? 1 : 0;
    }
    const int kb_lo = cu_r[sq], kb_hi = cu_r[sq + 1];
    const int ck0 = cu_r[sg0] & ~31;
    const int kend = cu_r[sg1 + 1];
    const int nchunk = (kend - ck0 + 31) >> 5;

    // Q fragments (B-operand: col=ln5=query, k = kt*16 + hi*8 + j)
    bf16x8 qh[5], ql[5];
    {
      const float* qrow = qf + (size_t)q_my * HID + h * HD;
#pragma unroll
      for (int kt = 0; kt < 5; ++kt) {
        const int d0 = kt * 16 + hi * 8;
        float4 a0 = *(const float4*)(qrow + d0);
        float4 a1 = *(const float4*)(qrow + d0 + 4);
        float va[8] = {a0.x, a0.y, a0.z, a0.w, a1.x, a1.y, a1.z, a1.w};
        bf16x8 hf, lf;
#pragma unroll
        for (int j = 0; j < 8; ++j) {
          float v = va[j] * qsc;
          unsigned short hu = f2bf(v);
          hf[j] = us2bf(hu);
          lf[j] = us2bf(f2bf(v - bf2f(hu)));
        }
        qh[kt] = hf; ql[kt] = lf;
      }
    }

    f32x16 O0, O1, O2;
#pragma unroll
    for (int r = 0; r < 16; ++r) { O0[r] = 0.f; O1[r] = 0.f; O2[r] = 0.f; }
    float m_i = -1e30f, l_i = 0.f;

    const unsigned short* gkh = khi + (size_t)h * SEQ * 80;
    const unsigned short* gkl = klo + (size_t)h * SEQ * 80;
    const unsigned short* gvh = vthi + (size_t)h * HD * SEQ;
    const unsigned short* gvl = vtlo + (size_t)h * HD * SEQ;

    // prologue: stage K(0)
    {
      const size_t kb = (size_t)ck0 * 80;
#pragma unroll
      for (int i = 0; i < 5; ++i) dma16(gkh + kb + koff[i], sKh + i * 512);
#pragma unroll
      for (int i = 0; i < 5; ++i) dma16(gkl + kb + koff[i], sKl + i * 512);
    }

    for (int ci = 0; ci < nchunk; ++ci) {
      const int ck = ck0 + ci * 32;
      // drain K(ci) (only K dmas outstanding; issued a full chunk earlier)
      asm volatile("s_waitcnt vmcnt(0)" ::: "memory");

      // V register loads for this chunk: issue BEFORE the K(i+1) dma batch
      // so the compiler's PV waits leave the K prefetch in flight.
      const int k0o = ck + hi * 8;       // KT=0 keys
      const int k1o = ck + 16 + hi * 8;  // KT=1 keys
      bf16x8 v0ha = *(const bf16x8*)&gvh[vra + k0o];
      bf16x8 v0hb = *(const bf16x8*)&gvh[vrb + k0o];
      bf16x8 v0hc = *(const bf16x8*)&gvh[vrc + k0o];
      bf16x8 v0la = *(const bf16x8*)&gvl[vra + k0o];
      bf16x8 v0lb = *(const bf16x8*)&gvl[vrb + k0o];
      bf16x8 v0lc = *(const bf16x8*)&gvl[vrc + k0o];
      bf16x8 v1ha = *(const bf16x8*)&gvh[vra + k1o];
      bf16x8 v1hb = *(const bf16x8*)&gvh[vrb + k1o];
      bf16x8 v1hc = *(const bf16x8*)&gvh[vrc + k1o];
      bf16x8 v1la = *(const bf16x8*)&gvl[vra + k1o];
      bf16x8 v1lb = *(const bf16x8*)&gvl[vrb + k1o];
      bf16x8 v1lc = *(const bf16x8*)&gvl[vrc + k1o];

      // ---- QK: S^T = K.Q^T (15 MFMA) ----
      f32x16 sc;
#pragma unroll
      for (int r = 0; r < 16; ++r) sc[r] = 0.f;
      __builtin_amdgcn_s_setprio(1);
#pragma unroll
      for (int kd = 0; kd < 5; ++kd) {
        const int col = ccol[kd];
        bf16x8 kh = *(const bf16x8*)&sKh[ln5 * 80 + col];
        bf16x8 kl = *(const bf16x8*)&sKl[ln5 * 80 + col];
        sc = MFMA32(kh, qh[kd], sc);
        sc = MFMA32(kh, ql[kd], sc);
        sc = MFMA32(kl, qh[kd], sc);
      }
      __builtin_amdgcn_s_setprio(0);

      // stage K(ci+1): K-buf free after the reads above; hides under SM+PV
      __builtin_amdgcn_sched_barrier(0);
      if (ci + 1 < nchunk) {
        const size_t kb = (size_t)(ck + 32) * 80;
#pragma unroll
        for (int i = 0; i < 5; ++i) dma16(gkh + kb + koff[i], sKh + i * 512);
#pragma unroll
        for (int i = 0; i < 5; ++i) dma16(gkl + kb + koff[i], sKl + i * 512);
      }

      // ---- mask + online softmax (lane-local; key = (r&3)+8*(r>>2)+4*hi) ----
      float mx = -1e30f;
      {
        const int kb = ck + 4 * hi;
#pragma unroll
        for (int r = 0; r < 16; ++r) {
          const int kg = kb + (r & 3) + 8 * (r >> 2);
          float v = (kg >= kb_lo && kg < kb_hi) ? sc[r] : -1e30f;
          sc[r] = v;
          mx = fmaxf(mx, v);
        }
      }
      mx = fmaxf(mx, __shfl_xor(mx, 32));
      const float mnew = fmaxf(m_i, mx);
      const float alpha = exp2f(m_i - mnew);
      float ps = 0.f;
#pragma unroll
      for (int r = 0; r < 16; ++r) {
        const float s = sc[r];
        const float p = (s > -1e29f) ? exp2f(s - mnew) : 0.f;
        ps += p;
        sc[r] = p;
      }
      ps += __shfl_xor(ps, 32);
      l_i = l_i * alpha + ps;
      m_i = mnew;
#pragma unroll
      for (int r = 0; r < 16; ++r) { O0[r] *= alpha; O1[r] *= alpha; O2[r] *= alpha; }

      // ---- PV: O^T += V^T.P (2 steps x 9 MFMA); V already in registers ----
      __builtin_amdgcn_s_setprio(1);
#pragma unroll
      for (int KT = 0; KT < 2; ++KT) {
        unsigned int A1 = cvtpk(sc[KT * 8 + 0], sc[KT * 8 + 1]);
        unsigned int A2 = cvtpk(sc[KT * 8 + 2], sc[KT * 8 + 3]);
        unsigned int B1 = cvtpk(sc[KT * 8 + 4], sc[KT * 8 + 5]);
        unsigned int B2 = cvtpk(sc[KT * 8 + 6], sc[KT * 8 + 7]);
        float e0 = sc[KT * 8 + 0] - lo2f(A1), e1 = sc[KT * 8 + 1] - hi2f(A1);
        float e2 = sc[KT * 8 + 2] - lo2f(A2), e3 = sc[KT * 8 + 3] - hi2f(A2);
        float e4 = sc[KT * 8 + 4] - lo2f(B1), e5 = sc[KT * 8 + 5] - hi2f(B1);
        float e6 = sc[KT * 8 + 6] - lo2f(B2), e7 = sc[KT * 8 + 7] - hi2f(B2);
        unsigned int C1 = cvtpk(e0, e1), C2 = cvtpk(e2, e3);
        unsigned int D1 = cvtpk(e4, e5), D2 = cvtpk(e6, e7);
        unsigned int T1 = (unsigned int)__shfl_xor((int)(hi ? A1 : B1), 32);
        unsigned int T2 = (unsigned int)__shfl_xor((int)(hi ? A2 : B2), 32);
        unsigned int U1 = (unsigned int)__shfl_xor((int)(hi ? C1 : D1), 32);
        unsigned int U2 = (unsigned int)__shfl_xor((int)(hi ? C2 : D2), 32);
        union { unsigned int w[4]; bf16x8 v; } ph_, pl_;
        ph_.w[0] = hi ? T1 : A1;  ph_.w[1] = hi ? T2 : A2;
        ph_.w[2] = hi ? B1 : T1;  ph_.w[3] = hi ? B2 : T2;
        pl_.w[0] = hi ? U1 : C1;  pl_.w[1] = hi ? U2 : C2;
        pl_.w[2] = hi ? D1 : U1;  pl_.w[3] = hi ? D2 : U2;
        bf16x8 vh0 = KT ? v1ha : v0ha;
        bf16x8 vh1 = KT ? v1hb : v0hb;
        bf16x8 vh2 = KT ? v1hc : v0hc;
        bf16x8 vl0 = KT ? v1la : v0la;
        bf16x8 vl1 = KT ? v1lb : v0lb;
        bf16x8 vl2 = KT ? v1lc : v0lc;
        O0 = MFMA32(vh0, ph_.v, O0); O1 = MFMA32(vh1, ph_.v, O1);
        O2 = MFMA32(vh2, ph_.v, O2);
        O0 = MFMA32(vl0, ph_.v, O0); O1 = MFMA32(vl1, ph_.v, O1);
        O2 = MFMA32(vl2, ph_.v, O2);
        O0 = MFMA32(vh0, pl_.v, O0); O1 = MFMA32(vh1, pl_.v, O1);
        O2 = MFMA32(vh2, pl_.v, O2);
      }
      __builtin_amdgcn_s_setprio(0);
    }

    // ---- epilogue: normalize + direct stores (C-layout d-quads) ----
    const float inv = 1.0f / l_i;
    unsigned short* orow = ohi + (size_t)q_my * HID + h * HD + 4 * hi;
#pragma unroll
    for (int j = 0; j < 4; ++j) {
      unsigned long long w =
          (unsigned long long)cvtpk(O0[4 * j] * inv, O0[4 * j + 1] * inv) |
          ((unsigned long long)cvtpk(O0[4 * j + 2] * inv, O0[4 * j + 3] * inv) << 32);
      *(unsigned long long*)&orow[8 * j] = w;
    }
#pragma unroll
    for (int j = 0; j < 4; ++j) {
      unsigned long long w =
          (unsigned long long)cvtpk(O1[4 * j] * inv, O1[4 * j + 1] * inv) |
          ((unsigned long long)cvtpk(O1[4 * j + 2] * inv, O1[4 * j + 3] * inv) << 32);
      *(unsigned long long*)&orow[32 + 8 * j] = w;
    }
#pragma unroll
    for (int j = 0; j < 2; ++j) {
      unsigned long long w =
          (unsigned long long)cvtpk(O2[4 * j] * inv, O2[4 * j + 1] * inv) |
          ((unsigned long long)cvtpk(O2[4 * j + 2] * inv, O2[4 * j + 3] * inv) << 32);
      *(unsigned long long*)&orow[64 + 8 * j] = w;
    }
  }
}

// ---------------- host launcher ---------------------------------------------
extern "C" void kernel_launch(void* const* d_in, const int* in_sizes, int n_in,
                              void* d_out, int out_size, void* d_ws, size_t ws_size,
                              hipStream_t stream) {
  const float* x      = (const float*)d_in[0];
  const int*   cu     = (const int*)d_in[1];
  const float* cs     = (const float*)d_in[2];
  const float* sn     = (const float*)d_in[3];
  const float* w_qkv  = (const float*)d_in[4];
  const float* b_qkv  = (const float*)d_in[5];
  const float* w_proj = (const float*)d_in[6];
  const float* b_proj = (const float*)d_in[7];
  float* out = (float*)d_out;

  char* ws = (char*)d_ws;
  float*          qf     = (float*)(ws + 0);
  float*          kf     = (float*)(ws + 20971520ULL);
  unsigned short* vthi   = (unsigned short*)(ws + 20971520ULL);
  unsigned short* vtlo   = (unsigned short*)(ws + 31457280ULL);
  float*          vf     = (float*)(ws + 41943040ULL);
  unsigned short* o_hi   = (unsigned short*)(ws + 41943040ULL);
  unsigned short* x_hi   = (unsigned short*)(ws + 62914560ULL);
  unsigned short* khi    = (unsigned short*)(ws + 62914560ULL);
  unsigned short* klo    = (unsigned short*)(ws + 73400320ULL);
  unsigned short* wqt_hi = (unsigned short*)(ws + 83886080ULL);
  unsigned short* wqt_lo = (unsigned short*)(ws + 93716480ULL);
  unsigned short* wpt_hi = (unsigned short*)(ws + 103546880ULL);
  unsigned short* wpt_lo = (unsigned short*)(ws + 106823680ULL);
  unsigned int*   ctr    = (unsigned int*)(ws + 83886080ULL);        // dead wqt (8x64B)
  int*            perm   = (int*)(ws + 83886080ULL + 1024);          // dead wqt

  split_hi_kernel<<<5120, 256, 0, stream>>>(x, x_hi, 1310720);
  tsplit_kernel<<<dim3(120, 40), 256, 0, stream>>>(w_qkv, wqt_hi, wqt_lo, 1280, 3840);
  tsplit_kernel<<<dim3(40, 40), 256, 0, stream>>>(w_proj, wpt_hi, wpt_lo, 1280, 1280);
  gemm128_x2<<<dim3(30, 32), 256, 0, stream>>>(x_hi, wqt_hi, wqt_lo, b_qkv,
                                               qf, kf, vf, 4096, 3840, 1280);
  rope_pack_kernel<<<dim3(64, 16), 256, 0, stream>>>(qf, kf, cs, sn, khi, klo);
  vt_pack_kernel<<<dim3(64, 16), 256, 0, stream>>>(vf, vthi, vtlo);
  sched_kernel<<<1, 128, 0, stream>>>(cu, perm, ctr);
  attn_kernel<<<1024, 128, 0, stream>>>(qf, khi, klo, vthi, vtlo, cu, o_hi, perm, ctr);
  gemm128_x2<<<dim3(10, 32), 256, 0, stream>>>(o_hi, wpt_hi, wpt_lo, b_proj,
                                               out, nullptr, nullptr, 4096, 1280, 1280);
}

// Round 10
// 370.621 us; speedup vs baseline: 1.1185x; 1.1185x over previous
//
#include <hip/hip_runtime.h>
#include <cstdint>
#include <cstddef>

typedef __bf16 bf16x8 __attribute__((ext_vector_type(8)));
typedef float f32x4 __attribute__((ext_vector_type(4)));
typedef float f32x16 __attribute__((ext_vector_type(16)));

#define SEQ   4096
#define HID   1280
#define NH    16
#define HD    80

__device__ __forceinline__ unsigned short f2bf(float f) {
  unsigned int u = __float_as_uint(f);
  unsigned int r = u + 0x7FFFu + ((u >> 16) & 1u);   // RNE
  return (unsigned short)(r >> 16);
}
__device__ __forceinline__ float bf2f(unsigned short h) {
  return __uint_as_float(((unsigned int)h) << 16);
}
__device__ __forceinline__ __bf16 us2bf(unsigned short u) {
  union { unsigned short s; __bf16 b; } c; c.s = u; return c.b;
}
__device__ __forceinline__ void dma16(const void* g, void* l) {
  __builtin_amdgcn_global_load_lds((const __attribute__((address_space(1))) unsigned int*)g,
                                   (__attribute__((address_space(3))) unsigned int*)l, 16, 0, 0);
}
__device__ __forceinline__ unsigned int cvtpk(float a, float b) {
  unsigned int w;
  asm("v_cvt_pk_bf16_f32 %0, %1, %2" : "=v"(w) : "v"(a), "v"(b));
  return w;
}
__device__ __forceinline__ float lo2f(unsigned int w) { return __uint_as_float(w << 16); }
__device__ __forceinline__ float hi2f(unsigned int w) { return __uint_as_float(w & 0xffff0000u); }

// ---------------- split: f32 -> bf16 hi only ---------------------------------
__global__ __launch_bounds__(256) void split_hi_kernel(const float* __restrict__ x,
                                                       unsigned short* __restrict__ hi,
                                                       int n4) {
  int i = blockIdx.x * 256 + threadIdx.x;
  if (i >= n4) return;
  float4 v = *((const float4*)x + i);
  *((ushort4*)hi + i) = make_ushort4(f2bf(v.x), f2bf(v.y), f2bf(v.z), f2bf(v.w));
}

// ---------------- transpose + split weights (hi/lo) --------------------------
__global__ __launch_bounds__(256) void tsplit_kernel(const float* __restrict__ W,
                                                     unsigned short* __restrict__ Thi,
                                                     unsigned short* __restrict__ Tlo,
                                                     int K, int N) {
  __shared__ float tile[32][33];
  int n0 = blockIdx.x * 32, k0 = blockIdx.y * 32;
  int tx = threadIdx.x & 31, ty = threadIdx.x >> 5;
#pragma unroll
  for (int i = 0; i < 32; i += 8)
    tile[ty + i][tx] = W[(size_t)(k0 + ty + i) * N + n0 + tx];
  __syncthreads();
#pragma unroll
  for (int i = 0; i < 32; i += 8) {
    float v = tile[tx][ty + i];
    size_t idx = (size_t)(n0 + ty + i) * K + (size_t)(k0 + tx);
    unsigned short h = f2bf(v);
    Thi[idx] = h;
    Tlo[idx] = f2bf(v - bf2f(h));
  }
}

// ---------------- 128x128 DMA GEMM, 2-term (A bf16, B hi/lo) -----------------
__global__ __launch_bounds__(256, 3) void gemm128_x2(
    const unsigned short* __restrict__ A, const unsigned short* __restrict__ Bh,
    const unsigned short* __restrict__ Bl, const float* __restrict__ bias,
    float* __restrict__ out0, float* __restrict__ out1, float* __restrict__ out2,
    int M, int N, int K) {
  __shared__ __align__(16) unsigned short sALL[3 * 8192];  // [A | Bh | Bl]

  const int t = threadIdx.x;
  const int lane = t & 63, wave = t >> 6;
  const int c16 = lane & 15, quad = lane >> 4;
  const int bm = blockIdx.y * 128, bn = blockIdx.x * 128;
  const int wr = (wave >> 1) * 64, wc = (wave & 1) * 64;
  const int lrow = lane >> 3;
  const int lswz = (lane & 7) ^ lrow;

  f32x4 acc[4][4];
#pragma unroll
  for (int i = 0; i < 4; ++i)
#pragma unroll
    for (int j = 0; j < 4; ++j) acc[i][j] = (f32x4){0.f, 0.f, 0.f, 0.f};

  const unsigned short* gp[12];
#pragma unroll
  for (int i = 0; i < 12; ++i) {
    const int ua = wave * 12 + i;
    const int arr = ua >> 4, sub = ua & 15;
    const unsigned short* g = (arr == 0) ? A : (arr == 1) ? Bh : Bl;
    const int rowg = ((arr == 0) ? bm : bn) + sub * 8 + lrow;
    gp[i] = g + (size_t)rowg * K + lswz * 8;
  }

  for (int k0 = 0; k0 < K; k0 += 64) {
    __syncthreads();
#pragma unroll
    for (int i = 0; i < 12; ++i)
      dma16(gp[i] + k0, &sALL[(wave * 12 + i) * 512]);
    __syncthreads();
#pragma unroll
    for (int ks = 0; ks < 2; ++ks) {
      bf16x8 a[4], bh[4], bl[4];
#pragma unroll
      for (int mi = 0; mi < 4; ++mi) {
        const int row = wr + mi * 16 + c16;
        const int off = row * 64 + (((ks * 4 + quad) ^ (row & 7)) * 8);
        a[mi] = *(const bf16x8*)&sALL[off];
      }
#pragma unroll
      for (int ni = 0; ni < 4; ++ni) {
        const int row = wc + ni * 16 + c16;
        const int off = row * 64 + (((ks * 4 + quad) ^ (row & 7)) * 8);
        bh[ni] = *(const bf16x8*)&sALL[8192 + off];
        bl[ni] = *(const bf16x8*)&sALL[16384 + off];
      }
#pragma unroll
      for (int mi = 0; mi < 4; ++mi)
#pragma unroll
        for (int ni = 0; ni < 4; ++ni) {
          acc[mi][ni] = __builtin_amdgcn_mfma_f32_16x16x32_bf16(a[mi], bh[ni], acc[mi][ni], 0, 0, 0);
          acc[mi][ni] = __builtin_amdgcn_mfma_f32_16x16x32_bf16(a[mi], bl[ni], acc[mi][ni], 0, 0, 0);
        }
    }
  }
#pragma unroll
  for (int ni = 0; ni < 4; ++ni) {
    int colg = bn + wc + ni * 16 + c16;
    float bv = bias[colg];
    float* op;
    int c = colg;
    if (c < 1280) op = out0;
    else if (c < 2560) { op = out1; c -= 1280; }
    else { op = out2; c -= 2560; }
#pragma unroll
    for (int mi = 0; mi < 4; ++mi)
#pragma unroll
      for (int r = 0; r < 4; ++r) {
        int rowg = bm + wr + mi * 16 + quad * 4 + r;
        op[(size_t)rowg * 1280 + c] = acc[mi][ni][r] + bv;
      }
  }
}

// ---------------- RoPE on q (in place, f32) + k -> packed bf16 hi/lo ---------
__global__ __launch_bounds__(256) void rope_pack_kernel(
    float* __restrict__ qf, const float* __restrict__ kf,
    const float* __restrict__ cs, const float* __restrict__ sn,
    unsigned short* __restrict__ khi, unsigned short* __restrict__ klo) {
  const int h = blockIdx.y;
  const int s = blockIdx.x * 64 + (threadIdx.x >> 2);
  const int p = threadIdx.x & 3;
  float* qrow = qf + (size_t)s * HID + h * HD;
  const float* krow = kf + (size_t)s * HID + h * HD;
  const float* cr = cs + (size_t)s * HD;
  const float* sr = sn + (size_t)s * HD;
  unsigned short* kh = khi + ((size_t)h * SEQ + s) * HD;
  unsigned short* kl = klo + ((size_t)h * SEQ + s) * HD;
#pragma unroll
  for (int j = 0; j < 10; ++j) {
    int d = 10 * p + j;           // 0..39
    float c0 = cr[d], s0 = sr[d], c1 = cr[d + 40], s1 = sr[d + 40];
    float q0 = qrow[d], q1 = qrow[d + 40];
    qrow[d]      = q0 * c0 - q1 * s0;
    qrow[d + 40] = q1 * c1 + q0 * s1;
    float k0 = krow[d], k1 = krow[d + 40];
    float kn0 = k0 * c0 - k1 * s0;
    float kn1 = k1 * c1 + k0 * s1;
    unsigned short h0 = f2bf(kn0), h1 = f2bf(kn1);
    kh[d] = h0;      kl[d] = f2bf(kn0 - bf2f(h0));
    kh[d + 40] = h1; kl[d + 40] = f2bf(kn1 - bf2f(h1));
  }
}

// ---------------- pack V^T: f32 [s][1280] -> bf16 hi/lo [h][80][4096] --------
__global__ __launch_bounds__(256) void vt_pack_kernel(const float* __restrict__ vf,
                                                      unsigned short* __restrict__ vthi,
                                                      unsigned short* __restrict__ vtlo) {
  __shared__ unsigned short sTh[80][72];
  __shared__ unsigned short sTl[80][72];
  const int h = blockIdx.y;
  const int s0 = blockIdx.x * 64;
  const int t = threadIdx.x;
  {
    int row = t >> 2, p = (t & 3) * 20;
    const float* src = vf + (size_t)(s0 + row) * HID + h * HD + p;
#pragma unroll
    for (int i = 0; i < 5; ++i) {
      float4 v = *(const float4*)(src + 4 * i);
      float vv[4] = {v.x, v.y, v.z, v.w};
#pragma unroll
      for (int j = 0; j < 4; ++j) {
        int d = p + 4 * i + j;
        unsigned short hu = f2bf(vv[j]);
        sTh[d][row] = hu;
        sTl[d][row] = f2bf(vv[j] - bf2f(hu));
      }
    }
  }
  __syncthreads();
  if (t < 160) {
    int d = t >> 1, half = (t & 1) * 32;
    size_t base = (size_t)(h * HD + d) * SEQ + s0 + half;
#pragma unroll
    for (int i = 0; i < 8; ++i) {
      *(ushort4*)&vthi[base + 4 * i] = *(ushort4*)&sTh[d][half + 4 * i];
      *(ushort4*)&vtlo[base + 4 * i] = *(ushort4*)&sTl[d][half + 4 * i];
    }
  }
}

// ---------------- scheduler: 8 per-XCD LPT queues of 128 units ---------------
// Unit = 64-query tile x head. Queue x: heads {2x,2x+1} x 64 tiles in
// descending-weight order (weights head-independent -> exact cross-XCD balance).
__global__ __launch_bounds__(128) void sched_kernel(const int* __restrict__ cu,
                                                    int* __restrict__ perm,
                                                    unsigned int* __restrict__ ctr) {
  __shared__ int w[64];
  const int t = threadIdx.x;
  if (t < 8) ctr[t * 16] = 0u;   // 8 counters, 64B apart
  int cu_r[9];
#pragma unroll
  for (int i = 0; i < 9; ++i) cu_r[i] = cu[i];
  if (t < 64) {
    const int r0 = t * 64;
    int sg0 = 0, sg1 = 0;
#pragma unroll
    for (int i = 1; i < 8; ++i) {
      sg0 += (r0      >= cu_r[i]) ? 1 : 0;
      sg1 += (r0 + 63 >= cu_r[i]) ? 1 : 0;
    }
    const int ck0 = cu_r[sg0] & ~63;
    const int kend = cu_r[sg1 + 1];
    w[t] = (kend - ck0 + 63) >> 6;
  }
  __syncthreads();
  if (t < 64) {
    const int wt = w[t];
    int rank = 0;
    for (int i = 0; i < 64; ++i)
      rank += ((w[i] > wt) || (w[i] == wt && i < t)) ? 1 : 0;
#pragma unroll
    for (int x = 0; x < 8; ++x) {
      perm[x * 128 + rank * 2 + 0] = (2 * x) * 64 + t;
      perm[x * 128 + rank * 2 + 1] = (2 * x + 1) * 64 + t;
    }
  }
}

// ---------------- attention: 2-wave blocks, shared staging, XCD LPT queues ---
// 768 blocks x 128 thr (96 slots/XCD pulling 128 units/XCD, LPT refill).
// Unit = 64 queries; wave w owns 32 (C-columns, 32x32 MFMA). Shared staging:
// per 64-key chunk, wave0 DMAs K-hi + V-hi planes, wave1 the lo planes
// (40960B LDS total = 4 blocks/CU exactly; 10B staged per query-key pair).
// R5-verified two-barrier pipeline (K(i+1) rides PV, V(i+1) rides next QK;
// __syncthreads provides all vmcnt drains). Inner math = R8-verified:
// lane-local softmax (exp2), cvt_pk+shfl P-build, direct epilogue stores.

#define MFMA32(A, B, C) __builtin_amdgcn_mfma_f32_32x32x16_bf16(A, B, C, 0, 0, 0)

__global__ __launch_bounds__(128, 2) void attn_kernel(
    const float* __restrict__ qf, const unsigned short* __restrict__ khi,
    const unsigned short* __restrict__ klo, const unsigned short* __restrict__ vthi,
    const unsigned short* __restrict__ vtlo, const int* __restrict__ cu,
    unsigned short* __restrict__ ohi, const int* __restrict__ perm,
    unsigned int* __restrict__ ctr) {
  __shared__ __align__(16) unsigned short sAll[20480];   // 40960 B exactly
  unsigned short* const sKh = sAll;                      // [64 key][80 d] sigma
  unsigned short* const sKl = sAll + 5120;
  unsigned short* const sVh = sAll + 10240;              // [80 d][64 key] sigma
  unsigned short* const sVl = sAll + 15360;
  unsigned int* const s_u = (unsigned int*)sAll;         // overlay (pull window only)

  const int t = threadIdx.x;
  const int lane = t & 63, wave = t >> 6;       // 2 waves
  const int ln5 = lane & 31;                    // query col / frag row
  const int hi  = lane >> 5;                    // k-half
  const int ln7 = lane & 7;
  const int xcd = blockIdx.x & 7;

  int cu_r[9];
#pragma unroll
  for (int i = 0; i < 9; ++i) cu_r[i] = cu[i];

  // K DMA source offsets: granule G = i*64+lane (640 total) -> key=G/10,
  // pos=G%10, src col = pos^(key&7) for pos<8 else pos (involution)
  int koff[10];
#pragma unroll
  for (int i = 0; i < 10; ++i) {
    const int G = i * 64 + lane;
    const int key = (G * 205) >> 11;            // exact /10 for G<1024
    const int p = G - key * 10;
    const int cl = (p < 8) ? (p ^ (key & 7)) : p;
    koff[i] = key * 80 + cl * 8;
  }
  // V DMA source offsets: granule G = i*64+lane -> d=G>>3, gc=G&7,
  // logical g = gc ^ (d&7)  (involution)
  int voff[10];
#pragma unroll
  for (int i = 0; i < 10; ++i) {
    const int G = i * 64 + lane;
    const int d = G >> 3, gc = G & 7;
    const int g = gc ^ (d & 7);
    voff[i] = d * SEQ + g * 8;
  }
  // K read columns (shorts) per kd (same for rows ln5 and 32+ln5)
  int ccol[5];
#pragma unroll
  for (int c = 0; c < 5; ++c)
    ccol[c] = (c < 4) ? ((((2 * c) + hi) ^ ln7) * 8) : ((8 + hi) * 8);
  // V read column (shorts) per PV step j (keys 16j..16j+15, granule 2j+hi)
  int gcol[4];
#pragma unroll
  for (int c = 0; c < 4; ++c)
    gcol[c] = (((2 * c) + hi) ^ ln7) * 8;

  const float qsc = 0.11180339887498949f * 1.4426950408889634f;  // *log2(e)

  for (;;) {
    __syncthreads();                         // prev unit fully done with LDS
    if (t == 0) s_u[0] = atomicAdd(&ctr[xcd * 16], 1u);
    __syncthreads();
    const unsigned int idx = s_u[0];
    if (idx >= 128u) break;
    const int uu = perm[xcd * 128 + idx];
    const int h = uu >> 6;
    const int r0 = (uu & 63) * 64;

    const int q_my = r0 + wave * 32 + ln5;
    int sq = 0, sg0 = 0, sg1 = 0;
#pragma unroll
    for (int i = 1; i < 8; ++i) {
      sq  += (q_my    >= cu_r[i]) ? 1 : 0;
      sg0 += (r0      >= cu_r[i]) ? 1 : 0;
      sg1 += (r0 + 63 >= cu_r[i]) ? 1 : 0;
    }
    const int kb_lo = cu_r[sq], kb_hi = cu_r[sq + 1];
    const int ck0 = cu_r[sg0] & ~63;
    const int kend = cu_r[sg1 + 1];
    const int nchunk = (kend - ck0 + 63) >> 6;

    // Q fragments (B-operand: col=ln5=query, k = kt*16 + hi*8 + j)
    bf16x8 qh[5], ql[5];
    {
      const float* qrow = qf + (size_t)q_my * HID + h * HD;
#pragma unroll
      for (int kt = 0; kt < 5; ++kt) {
        const int d0 = kt * 16 + hi * 8;
        float4 a0 = *(const float4*)(qrow + d0);
        float4 a1 = *(const float4*)(qrow + d0 + 4);
        float va[8] = {a0.x, a0.y, a0.z, a0.w, a1.x, a1.y, a1.z, a1.w};
        bf16x8 hf, lf;
#pragma unroll
        for (int j = 0; j < 8; ++j) {
          float v = va[j] * qsc;
          unsigned short hu = f2bf(v);
          hf[j] = us2bf(hu);
          lf[j] = us2bf(f2bf(v - bf2f(hu)));
        }
        qh[kt] = hf; ql[kt] = lf;
      }
    }

    f32x16 O0, O1, O2;
#pragma unroll
    for (int r = 0; r < 16; ++r) { O0[r] = 0.f; O1[r] = 0.f; O2[r] = 0.f; }
    float m_i = -1e30f, l_i = 0.f;

    const unsigned short* gkh = khi + (size_t)h * SEQ * 80;
    const unsigned short* gkl = klo + (size_t)h * SEQ * 80;
    const unsigned short* gvh = vthi + (size_t)h * HD * SEQ;
    const unsigned short* gvl = vtlo + (size_t)h * HD * SEQ;

    // stage K of chunk ck: wave0 -> hi plane, wave1 -> lo plane (10 dma each)
    auto STAGE_K = [&](int ck) {
      const unsigned short* gb = (wave ? gkl : gkh) + (size_t)ck * 80;
      unsigned short* lk = wave ? sKl : sKh;
#pragma unroll
      for (int i = 0; i < 10; ++i) dma16(gb + koff[i], lk + i * 512);
    };
    // stage V of chunk ck: wave0 -> hi plane, wave1 -> lo plane
    auto STAGE_V = [&](int ck) {
      const unsigned short* gb = wave ? gvl : gvh;
      unsigned short* lv = wave ? sVl : sVh;
#pragma unroll
      for (int i = 0; i < 10; ++i) dma16(gb + ck + voff[i], lv + i * 512);
    };

    STAGE_K(ck0);
    STAGE_V(ck0);
    __syncthreads();   // drain K(0)+V(0)

    for (int ci = 0; ci < nchunk; ++ci) {
      const int ck = ck0 + ci * 64;

      // ---- QK: S^T = K.Q^T, two 32-key tiles (30 MFMA) ----
      f32x16 sc0, sc1;
#pragma unroll
      for (int r = 0; r < 16; ++r) { sc0[r] = 0.f; sc1[r] = 0.f; }
      __builtin_amdgcn_s_setprio(1);
#pragma unroll
      for (int kd = 0; kd < 5; ++kd) {
        const int col = ccol[kd];
        bf16x8 kha = *(const bf16x8*)&sKh[ln5 * 80 + col];
        bf16x8 kla = *(const bf16x8*)&sKl[ln5 * 80 + col];
        bf16x8 khb = *(const bf16x8*)&sKh[(32 + ln5) * 80 + col];
        bf16x8 klb = *(const bf16x8*)&sKl[(32 + ln5) * 80 + col];
        sc0 = MFMA32(kha, qh[kd], sc0); sc1 = MFMA32(khb, qh[kd], sc1);
        sc0 = MFMA32(kha, ql[kd], sc0); sc1 = MFMA32(khb, ql[kd], sc1);
        sc0 = MFMA32(kla, qh[kd], sc0); sc1 = MFMA32(klb, qh[kd], sc1);
      }
      __builtin_amdgcn_s_setprio(0);

      // ---- mask + online softmax (lane-local; key = KT*32+(r&3)+8*(r>>2)+4hi)
      float mx = -1e30f;
#define MSK(SCV, KT2)                                                          \
      {                                                                        \
        const int kb = ck + (KT2) * 32 + 4 * hi;                               \
        _Pragma("unroll")                                                      \
        for (int r = 0; r < 16; ++r) {                                         \
          const int kg = kb + (r & 3) + 8 * (r >> 2);                          \
          float v = (kg >= kb_lo && kg < kb_hi) ? SCV[r] : -1e30f;             \
          SCV[r] = v;                                                          \
          mx = fmaxf(mx, v);                                                   \
        }                                                                      \
      }
      MSK(sc0, 0)
      MSK(sc1, 1)
#undef MSK
      mx = fmaxf(mx, __shfl_xor(mx, 32));
      const float mnew = fmaxf(m_i, mx);
      const float alpha = exp2f(m_i - mnew);
      float ps = 0.f;
#define EXPP(SCV)                                                              \
      _Pragma("unroll")                                                        \
      for (int r = 0; r < 16; ++r) {                                           \
        const float s = SCV[r];                                                \
        const float p = (s > -1e29f) ? exp2f(s - mnew) : 0.f;                  \
        ps += p;                                                               \
        SCV[r] = p;                                                            \
      }
      EXPP(sc0)
      EXPP(sc1)
#undef EXPP
      ps += __shfl_xor(ps, 32);
      l_i = l_i * alpha + ps;
      m_i = mnew;
#pragma unroll
      for (int r = 0; r < 16; ++r) { O0[r] *= alpha; O1[r] *= alpha; O2[r] *= alpha; }

      // ---- barrier A: K reads done; V(ci) DMA drained ----
      __syncthreads();
      if (ci + 1 < nchunk) STAGE_K(ck + 64);   // rides PV below

      // ---- PV: O^T += V^T.P (4 steps x 9 MFMA); P via cvt_pk + shfl ----
      __builtin_amdgcn_s_setprio(1);
#define PV_STEP(SCV, SUB, J)                                                   \
      {                                                                        \
        unsigned int A1 = cvtpk(SCV[(SUB)*8+0], SCV[(SUB)*8+1]);               \
        unsigned int A2 = cvtpk(SCV[(SUB)*8+2], SCV[(SUB)*8+3]);               \
        unsigned int B1 = cvtpk(SCV[(SUB)*8+4], SCV[(SUB)*8+5]);               \
        unsigned int B2 = cvtpk(SCV[(SUB)*8+6], SCV[(SUB)*8+7]);               \
        float e0 = SCV[(SUB)*8+0] - lo2f(A1), e1 = SCV[(SUB)*8+1] - hi2f(A1);  \
        float e2 = SCV[(SUB)*8+2] - lo2f(A2), e3 = SCV[(SUB)*8+3] - hi2f(A2);  \
        float e4 = SCV[(SUB)*8+4] - lo2f(B1), e5 = SCV[(SUB)*8+5] - hi2f(B1);  \
        float e6 = SCV[(SUB)*8+6] - lo2f(B2), e7 = SCV[(SUB)*8+7] - hi2f(B2);  \
        unsigned int C1 = cvtpk(e0, e1), C2 = cvtpk(e2, e3);                   \
        unsigned int D1 = cvtpk(e4, e5), D2 = cvtpk(e6, e7);                   \
        unsigned int T1 = (unsigned int)__shfl_xor((int)(hi ? A1 : B1), 32);   \
        unsigned int T2 = (unsigned int)__shfl_xor((int)(hi ? A2 : B2), 32);   \
        unsigned int U1 = (unsigned int)__shfl_xor((int)(hi ? C1 : D1), 32);   \
        unsigned int U2 = (unsigned int)__shfl_xor((int)(hi ? C2 : D2), 32);   \
        union { unsigned int w[4]; bf16x8 v; } ph_, pl_;                       \
        ph_.w[0] = hi ? T1 : A1;  ph_.w[1] = hi ? T2 : A2;                     \
        ph_.w[2] = hi ? B1 : T1;  ph_.w[3] = hi ? B2 : T2;                     \
        pl_.w[0] = hi ? U1 : C1;  pl_.w[1] = hi ? U2 : C2;                     \
        pl_.w[2] = hi ? D1 : U1;  pl_.w[3] = hi ? D2 : U2;                     \
        const int vc = gcol[J];                                                \
        bf16x8 vh0 = *(const bf16x8*)&sVh[ln5 * 64 + vc];                      \
        bf16x8 vh1 = *(const bf16x8*)&sVh[(32 + ln5) * 64 + vc];               \
        bf16x8 vh2 = *(const bf16x8*)&sVh[(64 + (ln5 & 15)) * 64 + vc];        \
        bf16x8 vl0 = *(const bf16x8*)&sVl[ln5 * 64 + vc];                      \
        bf16x8 vl1 = *(const bf16x8*)&sVl[(32 + ln5) * 64 + vc];               \
        bf16x8 vl2 = *(const bf16x8*)&sVl[(64 + (ln5 & 15)) * 64 + vc];        \
        O0 = MFMA32(vh0, ph_.v, O0); O1 = MFMA32(vh1, ph_.v, O1);              \
        O2 = MFMA32(vh2, ph_.v, O2);                                           \
        O0 = MFMA32(vl0, ph_.v, O0); O1 = MFMA32(vl1, ph_.v, O1);              \
        O2 = MFMA32(vl2, ph_.v, O2);                                           \
        O0 = MFMA32(vh0, pl_.v, O0); O1 = MFMA32(vh1, pl_.v, O1);              \
        O2 = MFMA32(vh2, pl_.v, O2);                                           \
      }
      PV_STEP(sc0, 0, 0)
      PV_STEP(sc0, 1, 1)
      PV_STEP(sc1, 0, 2)
      PV_STEP(sc1, 1, 3)
#undef PV_STEP
      __builtin_amdgcn_s_setprio(0);

      // ---- barrier B: V reads done; K(ci+1) DMA drained ----
      __syncthreads();
      if (ci + 1 < nchunk) STAGE_V(ck + 64);   // rides next QK + softmax
    }

    // ---- epilogue: normalize + direct stores (C-layout d-quads) ----
    const float inv = 1.0f / l_i;
    unsigned short* orow = ohi + (size_t)q_my * HID + h * HD + 4 * hi;
#pragma unroll
    for (int j = 0; j < 4; ++j) {
      unsigned long long w =
          (unsigned long long)cvtpk(O0[4 * j] * inv, O0[4 * j + 1] * inv) |
          ((unsigned long long)cvtpk(O0[4 * j + 2] * inv, O0[4 * j + 3] * inv) << 32);
      *(unsigned long long*)&orow[8 * j] = w;
    }
#pragma unroll
    for (int j = 0; j < 4; ++j) {
      unsigned long long w =
          (unsigned long long)cvtpk(O1[4 * j] * inv, O1[4 * j + 1] * inv) |
          ((unsigned long long)cvtpk(O1[4 * j + 2] * inv, O1[4 * j + 3] * inv) << 32);
      *(unsigned long long*)&orow[32 + 8 * j] = w;
    }
#pragma unroll
    for (int j = 0; j < 2; ++j) {
      unsigned long long w =
          (unsigned long long)cvtpk(O2[4 * j] * inv, O2[4 * j + 1] * inv) |
          ((unsigned long long)cvtpk(O2[4 * j + 2] * inv, O2[4 * j + 3] * inv) << 32);
      *(unsigned long long*)&orow[64 + 8 * j] = w;
    }
  }
}

// ---------------- host launcher ---------------------------------------------
extern "C" void kernel_launch(void* const* d_in, const int* in_sizes, int n_in,
                              void* d_out, int out_size, void* d_ws, size_t ws_size,
                              hipStream_t stream) {
  const float* x      = (const float*)d_in[0];
  const int*   cu     = (const int*)d_in[1];
  const float* cs     = (const float*)d_in[2];
  const float* sn     = (const float*)d_in[3];
  const float* w_qkv  = (const float*)d_in[4];
  const float* b_qkv  = (const float*)d_in[5];
  const float* w_proj = (const float*)d_in[6];
  const float* b_proj = (const float*)d_in[7];
  float* out = (float*)d_out;

  char* ws = (char*)d_ws;
  float*          qf     = (float*)(ws + 0);
  float*          kf     = (float*)(ws + 20971520ULL);
  unsigned short* vthi   = (unsigned short*)(ws + 20971520ULL);
  unsigned short* vtlo   = (unsigned short*)(ws + 31457280ULL);
  float*          vf     = (float*)(ws + 41943040ULL);
  unsigned short* o_hi   = (unsigned short*)(ws + 41943040ULL);
  unsigned short* x_hi   = (unsigned short*)(ws + 62914560ULL);
  unsigned short* khi    = (unsigned short*)(ws + 62914560ULL);
  unsigned short* klo    = (unsigned short*)(ws + 73400320ULL);
  unsigned short* wqt_hi = (unsigned short*)(ws + 83886080ULL);
  unsigned short* wqt_lo = (unsigned short*)(ws + 93716480ULL);
  unsigned short* wpt_hi = (unsigned short*)(ws + 103546880ULL);
  unsigned short* wpt_lo = (unsigned short*)(ws + 106823680ULL);
  unsigned int*   ctr    = (unsigned int*)(ws + 83886080ULL);        // dead wqt (8x64B)
  int*            perm   = (int*)(ws + 83886080ULL + 1024);          // dead wqt

  split_hi_kernel<<<5120, 256, 0, stream>>>(x, x_hi, 1310720);
  tsplit_kernel<<<dim3(120, 40), 256, 0, stream>>>(w_qkv, wqt_hi, wqt_lo, 1280, 3840);
  tsplit_kernel<<<dim3(40, 40), 256, 0, stream>>>(w_proj, wpt_hi, wpt_lo, 1280, 1280);
  gemm128_x2<<<dim3(30, 32), 256, 0, stream>>>(x_hi, wqt_hi, wqt_lo, b_qkv,
                                               qf, kf, vf, 4096, 3840, 1280);
  rope_pack_kernel<<<dim3(64, 16), 256, 0, stream>>>(qf, kf, cs, sn, khi, klo);
  vt_pack_kernel<<<dim3(64, 16), 256, 0, stream>>>(vf, vthi, vtlo);
  sched_kernel<<<1, 128, 0, stream>>>(cu, perm, ctr);
  attn_kernel<<<768, 128, 0, stream>>>(qf, khi, klo, vthi, vtlo, cu, o_hi, perm, ctr);
  gemm128_x2<<<dim3(10, 32), 256, 0, stream>>>(o_hi, wpt_hi, wpt_lo, b_proj,
                                               out, nullptr, nullptr, 4096, 1280, 1280);
}

// Round 11
// 368.874 us; speedup vs baseline: 1.1238x; 1.0047x over previous
//
#include <hip/hip_runtime.h>
#include <cstdint>
#include <cstddef>

typedef __bf16 bf16x8 __attribute__((ext_vector_type(8)));
typedef float f32x4 __attribute__((ext_vector_type(4)));
typedef float f32x16 __attribute__((ext_vector_type(16)));
typedef unsigned short u16x8 __attribute__((ext_vector_type(8)));

#define SEQ   4096
#define HID   1280
#define NH    16
#define HD    80

__device__ __forceinline__ unsigned short f2bf(float f) {
  unsigned int u = __float_as_uint(f);
  unsigned int r = u + 0x7FFFu + ((u >> 16) & 1u);   // RNE
  return (unsigned short)(r >> 16);
}
__device__ __forceinline__ float bf2f(unsigned short h) {
  return __uint_as_float(((unsigned int)h) << 16);
}
__device__ __forceinline__ __bf16 us2bf(unsigned short u) {
  union { unsigned short s; __bf16 b; } c; c.s = u; return c.b;
}
__device__ __forceinline__ void dma16(const void* g, void* l) {
  __builtin_amdgcn_global_load_lds((const __attribute__((address_space(1))) unsigned int*)g,
                                   (__attribute__((address_space(3))) unsigned int*)l, 16, 0, 0);
}
__device__ __forceinline__ unsigned int cvtpk(float a, float b) {
  unsigned int w;
  asm("v_cvt_pk_bf16_f32 %0, %1, %2" : "=v"(w) : "v"(a), "v"(b));
  return w;
}
__device__ __forceinline__ float lo2f(unsigned int w) { return __uint_as_float(w << 16); }
__device__ __forceinline__ float hi2f(unsigned int w) { return __uint_as_float(w & 0xffff0000u); }

// ---------------- split: f32 -> bf16 hi only ---------------------------------
__global__ __launch_bounds__(256) void split_hi_kernel(const float* __restrict__ x,
                                                       unsigned short* __restrict__ hi,
                                                       int n4) {
  int i = blockIdx.x * 256 + threadIdx.x;
  if (i >= n4) return;
  float4 v = *((const float4*)x + i);
  *((ushort4*)hi + i) = make_ushort4(f2bf(v.x), f2bf(v.y), f2bf(v.z), f2bf(v.w));
}

// ---------------- transpose + split weights (hi/lo) --------------------------
__global__ __launch_bounds__(256) void tsplit_kernel(const float* __restrict__ W,
                                                     unsigned short* __restrict__ Thi,
                                                     unsigned short* __restrict__ Tlo,
                                                     int K, int N) {
  __shared__ float tile[32][33];
  int n0 = blockIdx.x * 32, k0 = blockIdx.y * 32;
  int tx = threadIdx.x & 31, ty = threadIdx.x >> 5;
#pragma unroll
  for (int i = 0; i < 32; i += 8)
    tile[ty + i][tx] = W[(size_t)(k0 + ty + i) * N + n0 + tx];
  __syncthreads();
#pragma unroll
  for (int i = 0; i < 32; i += 8) {
    float v = tile[tx][ty + i];
    size_t idx = (size_t)(n0 + ty + i) * K + (size_t)(k0 + tx);
    unsigned short h = f2bf(v);
    Thi[idx] = h;
    Tlo[idx] = f2bf(v - bf2f(h));
  }
}

// ---------------- 128x128 DMA GEMM, 2-term (A bf16, B hi/lo) -----------------
__global__ __launch_bounds__(256, 3) void gemm128_x2(
    const unsigned short* __restrict__ A, const unsigned short* __restrict__ Bh,
    const unsigned short* __restrict__ Bl, const float* __restrict__ bias,
    float* __restrict__ out0, float* __restrict__ out1, float* __restrict__ out2,
    int M, int N, int K) {
  __shared__ __align__(16) unsigned short sALL[3 * 8192];  // [A | Bh | Bl]

  const int t = threadIdx.x;
  const int lane = t & 63, wave = t >> 6;
  const int c16 = lane & 15, quad = lane >> 4;
  const int bm = blockIdx.y * 128, bn = blockIdx.x * 128;
  const int wr = (wave >> 1) * 64, wc = (wave & 1) * 64;
  const int lrow = lane >> 3;
  const int lswz = (lane & 7) ^ lrow;

  f32x4 acc[4][4];
#pragma unroll
  for (int i = 0; i < 4; ++i)
#pragma unroll
    for (int j = 0; j < 4; ++j) acc[i][j] = (f32x4){0.f, 0.f, 0.f, 0.f};

  const unsigned short* gp[12];
#pragma unroll
  for (int i = 0; i < 12; ++i) {
    const int ua = wave * 12 + i;
    const int arr = ua >> 4, sub = ua & 15;
    const unsigned short* g = (arr == 0) ? A : (arr == 1) ? Bh : Bl;
    const int rowg = ((arr == 0) ? bm : bn) + sub * 8 + lrow;
    gp[i] = g + (size_t)rowg * K + lswz * 8;
  }

  for (int k0 = 0; k0 < K; k0 += 64) {
    __syncthreads();
#pragma unroll
    for (int i = 0; i < 12; ++i)
      dma16(gp[i] + k0, &sALL[(wave * 12 + i) * 512]);
    __syncthreads();
#pragma unroll
    for (int ks = 0; ks < 2; ++ks) {
      bf16x8 a[4], bh[4], bl[4];
#pragma unroll
      for (int mi = 0; mi < 4; ++mi) {
        const int row = wr + mi * 16 + c16;
        const int off = row * 64 + (((ks * 4 + quad) ^ (row & 7)) * 8);
        a[mi] = *(const bf16x8*)&sALL[off];
      }
#pragma unroll
      for (int ni = 0; ni < 4; ++ni) {
        const int row = wc + ni * 16 + c16;
        const int off = row * 64 + (((ks * 4 + quad) ^ (row & 7)) * 8);
        bh[ni] = *(const bf16x8*)&sALL[8192 + off];
        bl[ni] = *(const bf16x8*)&sALL[16384 + off];
      }
#pragma unroll
      for (int mi = 0; mi < 4; ++mi)
#pragma unroll
        for (int ni = 0; ni < 4; ++ni) {
          acc[mi][ni] = __builtin_amdgcn_mfma_f32_16x16x32_bf16(a[mi], bh[ni], acc[mi][ni], 0, 0, 0);
          acc[mi][ni] = __builtin_amdgcn_mfma_f32_16x16x32_bf16(a[mi], bl[ni], acc[mi][ni], 0, 0, 0);
        }
    }
  }
#pragma unroll
  for (int ni = 0; ni < 4; ++ni) {
    int colg = bn + wc + ni * 16 + c16;
    float bv = bias[colg];
    float* op;
    int c = colg;
    if (c < 1280) op = out0;
    else if (c < 2560) { op = out1; c -= 1280; }
    else { op = out2; c -= 2560; }
#pragma unroll
    for (int mi = 0; mi < 4; ++mi)
#pragma unroll
      for (int r = 0; r < 4; ++r) {
        int rowg = bm + wr + mi * 16 + quad * 4 + r;
        op[(size_t)rowg * 1280 + c] = acc[mi][ni][r] + bv;
      }
  }
}

// ---------------- RoPE on q (in place, f32) + k -> packed bf16 hi/lo ---------
__global__ __launch_bounds__(256) void rope_pack_kernel(
    float* __restrict__ qf, const float* __restrict__ kf,
    const float* __restrict__ cs, const float* __restrict__ sn,
    unsigned short* __restrict__ khi, unsigned short* __restrict__ klo) {
  const int h = blockIdx.y;
  const int s = blockIdx.x * 64 + (threadIdx.x >> 2);
  const int p = threadIdx.x & 3;
  float* qrow = qf + (size_t)s * HID + h * HD;
  const float* krow = kf + (size_t)s * HID + h * HD;
  const float* cr = cs + (size_t)s * HD;
  const float* sr = sn + (size_t)s * HD;
  unsigned short* kh = khi + ((size_t)h * SEQ + s) * HD;
  unsigned short* kl = klo + ((size_t)h * SEQ + s) * HD;
#pragma unroll
  for (int j = 0; j < 10; ++j) {
    int d = 10 * p + j;           // 0..39
    float c0 = cr[d], s0 = sr[d], c1 = cr[d + 40], s1 = sr[d + 40];
    float q0 = qrow[d], q1 = qrow[d + 40];
    qrow[d]      = q0 * c0 - q1 * s0;
    qrow[d + 40] = q1 * c1 + q0 * s1;
    float k0 = krow[d], k1 = krow[d + 40];
    float kn0 = k0 * c0 - k1 * s0;
    float kn1 = k1 * c1 + k0 * s1;
    unsigned short h0 = f2bf(kn0), h1 = f2bf(kn1);
    kh[d] = h0;      kl[d] = f2bf(kn0 - bf2f(h0));
    kh[d + 40] = h1; kl[d + 40] = f2bf(kn1 - bf2f(h1));
  }
}

// ---------------- pack V^T: f32 [s][1280] -> bf16 hi/lo [h][80][4096] --------
__global__ __launch_bounds__(256) void vt_pack_kernel(const float* __restrict__ vf,
                                                      unsigned short* __restrict__ vthi,
                                                      unsigned short* __restrict__ vtlo) {
  __shared__ unsigned short sTh[80][72];
  __shared__ unsigned short sTl[80][72];
  const int h = blockIdx.y;
  const int s0 = blockIdx.x * 64;
  const int t = threadIdx.x;
  {
    int row = t >> 2, p = (t & 3) * 20;
    const float* src = vf + (size_t)(s0 + row) * HID + h * HD + p;
#pragma unroll
    for (int i = 0; i < 5; ++i) {
      float4 v = *(const float4*)(src + 4 * i);
      float vv[4] = {v.x, v.y, v.z, v.w};
#pragma unroll
      for (int j = 0; j < 4; ++j) {
        int d = p + 4 * i + j;
        unsigned short hu = f2bf(vv[j]);
        sTh[d][row] = hu;
        sTl[d][row] = f2bf(vv[j] - bf2f(hu));
      }
    }
  }
  __syncthreads();
  if (t < 160) {
    int d = t >> 1, half = (t & 1) * 32;
    size_t base = (size_t)(h * HD + d) * SEQ + s0 + half;
#pragma unroll
    for (int i = 0; i < 8; ++i) {
      *(ushort4*)&vthi[base + 4 * i] = *(ushort4*)&sTh[d][half + 4 * i];
      *(ushort4*)&vtlo[base + 4 * i] = *(ushort4*)&sTl[d][half + 4 * i];
    }
  }
}

// ---------------- scheduler: snake-balanced static perm ----------------------
// 64 tile weights (head-independent). Rank tiles by weight desc. CU j of each
// XCD is assumed to co-host slots {j, j+32, j+64, j+96} (breadth-first fill);
// give them unit-ranks {j, 63-j, 64+j, 127-j} (snake) so every CU's total
// weight ~ constant and the two same-weight head-copies never co-reside.
// Unit encoding: h*64 + tile. Queue-free: purely static lookup.
__global__ __launch_bounds__(64) void sched_kernel(const int* __restrict__ cu,
                                                   int* __restrict__ perm) {
  __shared__ int w[64];
  __shared__ int tile_of_rank[64];
  const int t = threadIdx.x;     // 64 threads, one per tile
  int cu_r[9];
#pragma unroll
  for (int i = 0; i < 9; ++i) cu_r[i] = cu[i];
  {
    const int r0 = t * 64;
    int sg0 = 0, sg1 = 0;
#pragma unroll
    for (int i = 1; i < 8; ++i) {
      sg0 += (r0      >= cu_r[i]) ? 1 : 0;
      sg1 += (r0 + 63 >= cu_r[i]) ? 1 : 0;
    }
    const int ck0 = cu_r[sg0] & ~63;
    const int kend = cu_r[sg1 + 1];
    w[t] = (kend - ck0 + 63) >> 6;
  }
  __syncthreads();
  {
    const int wt = w[t];
    int rank = 0;
    for (int i = 0; i < 64; ++i)
      rank += ((w[i] > wt) || (w[i] == wt && i < t)) ? 1 : 0;
    tile_of_rank[rank] = t;
  }
  __syncthreads();
  for (int s = t; s < 128; s += 64) {
    const int j = s & 31, g = s >> 5;
    const int f = (g == 0) ? j : (g == 1) ? (63 - j) : (g == 2) ? (64 + j) : (127 - j);
    const int tau = tile_of_rank[f >> 1];
    const int p = f & 1;
#pragma unroll
    for (int x = 0; x < 8; ++x)
      perm[x * 128 + s] = (2 * x + p) * 64 + tau;
  }
}

// ---------------- attention (R5-verified inner; snake static map) ------------
// 1024 blocks x 128 thr (4 blocks/CU, fully resident). Block b: XCD x=b&7,
// slot s=b>>3; unit = perm[x*128+s] (snake-balanced, XCD-local heads 2x,2x+1).
// Wave owns 32 queries (C-columns, 32x32 MFMA). S^T = K.Q^T, softmax
// lane-local, P->B-frag via cvt_pk + shfl_xor(32), O^T = V^T.P.
// K sigma-permuted, V xor-swizzled; single-buffered 40960B LDS;
// two-barrier chunk pipeline (K(i+1) rides PV, V(i+1) rides next QK).

#define MFMA32(A, B, C) __builtin_amdgcn_mfma_f32_32x32x16_bf16(A, B, C, 0, 0, 0)

__global__ __launch_bounds__(128, 2) void attn_kernel(
    const float* __restrict__ qf, const unsigned short* __restrict__ khi,
    const unsigned short* __restrict__ klo, const unsigned short* __restrict__ vthi,
    const unsigned short* __restrict__ vtlo, const int* __restrict__ cu,
    unsigned short* __restrict__ ohi, const int* __restrict__ perm) {
  __shared__ __align__(16) unsigned short sAll[20480];   // 40960 B exactly
  unsigned short* const sKh = sAll;                      // [64 key][80 d] sigma-perm
  unsigned short* const sKl = sAll + 5120;
  unsigned short* const sVh = sAll + 10240;              // [80 d][64 key] xor-swz
  unsigned short* const sVl = sAll + 15360;

  const int t = threadIdx.x;
  const int lane = t & 63, wave = t >> 6;       // 2 waves
  const int ln5 = lane & 31;                    // query col / frag row
  const int hi  = lane >> 5;                    // k-group half
  const int ln7 = lane & 7;
  const int lr8 = lane >> 3;
  const int vswz = (lane & 7) ^ lr8;

  // snake-balanced static unit map
  const int u = perm[(blockIdx.x & 7) * 128 + (blockIdx.x >> 3)];
  const int h = u >> 6;
  const int r0 = (u & 63) * 64;

  int cu_r[9];
#pragma unroll
  for (int i = 0; i < 9; ++i) cu_r[i] = cu[i];

  const int q_my = r0 + wave * 32 + ln5;        // this lane's query row
  int sq = 0, sg0 = 0, sg1 = 0;
#pragma unroll
  for (int i = 1; i < 8; ++i) {
    sq  += (q_my    >= cu_r[i]) ? 1 : 0;
    sg0 += (r0      >= cu_r[i]) ? 1 : 0;
    sg1 += (r0 + 63 >= cu_r[i]) ? 1 : 0;
  }
  const int kb_lo = cu_r[sq], kb_hi = cu_r[sq + 1];
  const int ck0 = cu_r[sg0] & ~63;
  const int kend = cu_r[sg1 + 1];
  const int nchunk = (kend - ck0 + 63) >> 6;

  // 16B-column table: position of logical granule (2c+hi) under XOR-sigma
  int ccol[5];
#pragma unroll
  for (int c = 0; c < 5; ++c)
    ccol[c] = (c < 4) ? ((((2 * c) + hi) ^ ln7) * 8) : ((8 + hi) * 8);

  // K DMA source offsets (shorts): granule G = i*64+lane -> key=G/10, pos=G%10,
  // logical col = pos^(key&7) for pos<8 else pos
  int koff[10];
#pragma unroll
  for (int i = 0; i < 10; ++i) {
    const int G = i * 64 + lane;
    const int key = (G * 205) >> 11;            // exact /10 for G<1024
    const int p = G - key * 10;
    const int cl = (p < 8) ? (p ^ (key & 7)) : p;
    koff[i] = key * 80 + cl * 8;
  }

  // Q fragments (B-operand: col=ln5=query, k = kt*16 + hi*8 + j), scale folded
  const float qsc = 0.11180339887498949f;
  bf16x8 qh[5], ql[5];
  {
    const float* qrow = qf + (size_t)q_my * HID + h * HD;
#pragma unroll
    for (int kt = 0; kt < 5; ++kt) {
      const int d0 = kt * 16 + hi * 8;
      float4 a0 = *(const float4*)(qrow + d0);
      float4 a1 = *(const float4*)(qrow + d0 + 4);
      float va[8] = {a0.x, a0.y, a0.z, a0.w, a1.x, a1.y, a1.z, a1.w};
      bf16x8 hf, lf;
#pragma unroll
      for (int j = 0; j < 8; ++j) {
        float v = va[j] * qsc;
        unsigned short hu = f2bf(v);
        hf[j] = us2bf(hu);
        lf[j] = us2bf(f2bf(v - bf2f(hu)));
      }
      qh[kt] = hf; ql[kt] = lf;
    }
  }

  f32x16 O0, O1, O2;
#pragma unroll
  for (int r = 0; r < 16; ++r) { O0[r] = 0.f; O1[r] = 0.f; O2[r] = 0.f; }
  float m_i = -1e30f, l_i = 0.f;

  // stage K of chunk ck (sigma-permuted source, linear LDS dest)
  auto STAGE_K = [&](int ck) {
    const unsigned short* gk = (wave & 1) ? klo : khi;
    unsigned short* lk = (wave & 1) ? sKl : sKh;
    const unsigned short* gb = gk + ((size_t)h * SEQ + ck) * 80;
#pragma unroll
    for (int i2 = 0; i2 < 10; ++i2) dma16(gb + koff[i2], lk + i2 * 512);
  };
  // stage V^T of chunk ck (xor-swz via pre-swizzled source cols)
  auto STAGE_V = [&](int ck) {
    const unsigned short* gv = (wave & 1) ? vtlo : vthi;
    unsigned short* lv = (wave & 1) ? sVl : sVh;
#pragma unroll
    for (int i2 = 0; i2 < 10; ++i2)
      dma16(gv + (size_t)(h * HD + 8 * i2 + lr8) * SEQ + ck + vswz * 8, lv + i2 * 512);
  };

  STAGE_K(ck0);
  STAGE_V(ck0);
  __syncthreads();

  for (int ci = 0; ci < nchunk; ++ci) {
    const int ck = ck0 + ci * 64;

    // ---- QK: S^T = K.Q^T, two 32-key tiles ----
    f32x16 sc0, sc1;
#pragma unroll
    for (int r = 0; r < 16; ++r) { sc0[r] = 0.f; sc1[r] = 0.f; }
    __builtin_amdgcn_s_setprio(1);
#pragma unroll
    for (int kd = 0; kd < 5; ++kd) {
      const int col = ccol[kd];
      bf16x8 kha = *(const bf16x8*)&sKh[ln5 * 80 + col];
      bf16x8 kla = *(const bf16x8*)&sKl[ln5 * 80 + col];
      bf16x8 khb = *(const bf16x8*)&sKh[(32 + ln5) * 80 + col];
      bf16x8 klb = *(const bf16x8*)&sKl[(32 + ln5) * 80 + col];
      sc0 = MFMA32(kha, qh[kd], sc0); sc1 = MFMA32(khb, qh[kd], sc1);
      sc0 = MFMA32(kha, ql[kd], sc0); sc1 = MFMA32(khb, ql[kd], sc1);
      sc0 = MFMA32(kla, qh[kd], sc0); sc1 = MFMA32(klb, qh[kd], sc1);
    }
    __builtin_amdgcn_s_setprio(0);

    // ---- mask + online softmax (all lane-local; key = (r&3)+8*(r>>2)+4*hi) --
    float mx = -1e30f;
#define MSK(SCV, KT2)                                                          \
    {                                                                          \
      const int kb = ck + (KT2) * 32 + 4 * hi;                                 \
      _Pragma("unroll")                                                        \
      for (int r = 0; r < 16; ++r) {                                           \
        const int kg = kb + (r & 3) + 8 * (r >> 2);                            \
        float v = (kg >= kb_lo && kg < kb_hi) ? SCV[r] : -1e30f;               \
        SCV[r] = v;                                                            \
        mx = fmaxf(mx, v);                                                     \
      }                                                                        \
    }
    MSK(sc0, 0)
    MSK(sc1, 1)
#undef MSK
    mx = fmaxf(mx, __shfl_xor(mx, 32));
    const float mnew = fmaxf(m_i, mx);
    const float alpha = __expf(m_i - mnew);
    float ps = 0.f;
#define EXPP(SCV)                                                              \
    _Pragma("unroll")                                                          \
    for (int r = 0; r < 16; ++r) {                                             \
      const float s = SCV[r];                                                  \
      const float p = (s > -1e29f) ? __expf(s - mnew) : 0.f;                   \
      ps += p;                                                                 \
      SCV[r] = p;                                                              \
    }
    EXPP(sc0)
    EXPP(sc1)
#undef EXPP
    ps += __shfl_xor(ps, 32);
    l_i = l_i * alpha + ps;
    m_i = mnew;
#pragma unroll
    for (int r = 0; r < 16; ++r) { O0[r] *= alpha; O1[r] *= alpha; O2[r] *= alpha; }

    // ---- barrier A: K reads done; V(ci) DMA drained ----
    __syncthreads();
    if (ci + 1 < nchunk) STAGE_K(ck + 64);   // rides PV below

    // ---- PV: O^T += V^T.P ; P B-frag via cvt_pk + shfl_xor(32) exchange ----
    __builtin_amdgcn_s_setprio(1);
#define PV_STEP(SCV, SUB, KT)                                                  \
    {                                                                          \
      unsigned int A1 = cvtpk(SCV[(SUB)*8+0], SCV[(SUB)*8+1]);                 \
      unsigned int A2 = cvtpk(SCV[(SUB)*8+2], SCV[(SUB)*8+3]);                 \
      unsigned int B1 = cvtpk(SCV[(SUB)*8+4], SCV[(SUB)*8+5]);                 \
      unsigned int B2 = cvtpk(SCV[(SUB)*8+6], SCV[(SUB)*8+7]);                 \
      float e0 = SCV[(SUB)*8+0] - lo2f(A1), e1 = SCV[(SUB)*8+1] - hi2f(A1);    \
      float e2 = SCV[(SUB)*8+2] - lo2f(A2), e3 = SCV[(SUB)*8+3] - hi2f(A2);    \
      float e4 = SCV[(SUB)*8+4] - lo2f(B1), e5 = SCV[(SUB)*8+5] - hi2f(B1);    \
      float e6 = SCV[(SUB)*8+6] - lo2f(B2), e7 = SCV[(SUB)*8+7] - hi2f(B2);    \
      unsigned int C1 = cvtpk(e0, e1), C2 = cvtpk(e2, e3);                     \
      unsigned int D1 = cvtpk(e4, e5), D2 = cvtpk(e6, e7);                     \
      unsigned int T1 = (unsigned int)__shfl_xor((int)(hi ? A1 : B1), 32);     \
      unsigned int T2 = (unsigned int)__shfl_xor((int)(hi ? A2 : B2), 32);     \
      unsigned int U1 = (unsigned int)__shfl_xor((int)(hi ? C1 : D1), 32);     \
      unsigned int U2 = (unsigned int)__shfl_xor((int)(hi ? C2 : D2), 32);     \
      union { unsigned int w[4]; bf16x8 v; } ph_, pl_;                         \
      ph_.w[0] = hi ? T1 : A1;  ph_.w[1] = hi ? T2 : A2;                       \
      ph_.w[2] = hi ? B1 : T1;  ph_.w[3] = hi ? B2 : T2;                       \
      pl_.w[0] = hi ? U1 : C1;  pl_.w[1] = hi ? U2 : C2;                       \
      pl_.w[2] = hi ? D1 : U1;  pl_.w[3] = hi ? D2 : U2;                       \
      const int vc = ccol[KT];                                                 \
      bf16x8 vh0 = *(const bf16x8*)&sVh[ln5 * 64 + vc];                        \
      bf16x8 vh1 = *(const bf16x8*)&sVh[(32 + ln5) * 64 + vc];                 \
      bf16x8 vh2 = *(const bf16x8*)&sVh[(64 + (ln5 & 15)) * 64 + vc];          \
      bf16x8 vl0 = *(const bf16x8*)&sVl[ln5 * 64 + vc];                        \
      bf16x8 vl1 = *(const bf16x8*)&sVl[(32 + ln5) * 64 + vc];                 \
      bf16x8 vl2 = *(const bf16x8*)&sVl[(64 + (ln5 & 15)) * 64 + vc];          \
      O0 = MFMA32(vh0, ph_.v, O0); O1 = MFMA32(vh1, ph_.v, O1);                \
      O2 = MFMA32(vh2, ph_.v, O2);                                             \
      O0 = MFMA32(vl0, ph_.v, O0); O1 = MFMA32(vl1, ph_.v, O1);                \
      O2 = MFMA32(vl2, ph_.v, O2);                                             \
      O0 = MFMA32(vh0, pl_.v, O0); O1 = MFMA32(vh1, pl_.v, O1);                \
      O2 = MFMA32(vh2, pl_.v, O2);                                             \
    }
    PV_STEP(sc0, 0, 0)
    PV_STEP(sc0, 1, 1)
    PV_STEP(sc1, 0, 2)
    PV_STEP(sc1, 1, 3)
#undef PV_STEP
    __builtin_amdgcn_s_setprio(0);

    // ---- barrier B: V reads done; K(ci+1) DMA drained ----
    __syncthreads();
    if (ci + 1 < nchunk) STAGE_V(ck + 64);   // rides next QK + softmax
  }

  // ---- epilogue: normalize (lane-local), transpose via LDS, store ----------
  const float inv = 1.0f / l_i;
  unsigned short* tr = sAll + wave * 3072;     // [32 q][96 d] shorts
#define WR(OV, DT)                                                             \
  _Pragma("unroll")                                                            \
  for (int r = 0; r < 16; r += 2) {                                            \
    if ((DT) < 2 || r < 8) {                                                   \
      const int d = (DT) * 32 + (r & 3) + 8 * (r >> 2) + 4 * hi;               \
      unsigned int w = cvtpk(OV[r] * inv, OV[r + 1] * inv);                    \
      *(unsigned int*)&tr[ln5 * 96 + d] = w;                                   \
    }                                                                          \
  }
  WR(O0, 0)
  WR(O1, 1)
  WR(O2, 2)
#undef WR
  __syncthreads();
  {
    const int qq = lane >> 1, part = lane & 1;
    const unsigned short* src = tr + qq * 96 + part * 40;
    unsigned short* dst = ohi + (size_t)(r0 + wave * 32 + qq) * HID + h * HD + part * 40;
#pragma unroll
    for (int i = 0; i < 5; ++i)
      *(u16x8*)&dst[i * 8] = *(const u16x8*)&src[i * 8];
  }
}

// ---------------- host launcher ---------------------------------------------
extern "C" void kernel_launch(void* const* d_in, const int* in_sizes, int n_in,
                              void* d_out, int out_size, void* d_ws, size_t ws_size,
                              hipStream_t stream) {
  const float* x      = (const float*)d_in[0];
  const int*   cu     = (const int*)d_in[1];
  const float* cs     = (const float*)d_in[2];
  const float* sn     = (const float*)d_in[3];
  const float* w_qkv  = (const float*)d_in[4];
  const float* b_qkv  = (const float*)d_in[5];
  const float* w_proj = (const float*)d_in[6];
  const float* b_proj = (const float*)d_in[7];
  float* out = (float*)d_out;

  char* ws = (char*)d_ws;
  float*          qf     = (float*)(ws + 0);
  float*          kf     = (float*)(ws + 20971520ULL);
  unsigned short* vthi   = (unsigned short*)(ws + 20971520ULL);
  unsigned short* vtlo   = (unsigned short*)(ws + 31457280ULL);
  float*          vf     = (float*)(ws + 41943040ULL);
  unsigned short* o_hi   = (unsigned short*)(ws + 41943040ULL);
  unsigned short* x_hi   = (unsigned short*)(ws + 62914560ULL);
  unsigned short* khi    = (unsigned short*)(ws + 62914560ULL);
  unsigned short* klo    = (unsigned short*)(ws + 73400320ULL);
  unsigned short* wqt_hi = (unsigned short*)(ws + 83886080ULL);
  unsigned short* wqt_lo = (unsigned short*)(ws + 93716480ULL);
  unsigned short* wpt_hi = (unsigned short*)(ws + 103546880ULL);
  unsigned short* wpt_lo = (unsigned short*)(ws + 106823680ULL);
  int*            perm   = (int*)(ws + 83886080ULL);                 // dead wqt

  split_hi_kernel<<<5120, 256, 0, stream>>>(x, x_hi, 1310720);
  tsplit_kernel<<<dim3(120, 40), 256, 0, stream>>>(w_qkv, wqt_hi, wqt_lo, 1280, 3840);
  tsplit_kernel<<<dim3(40, 40), 256, 0, stream>>>(w_proj, wpt_hi, wpt_lo, 1280, 1280);
  gemm128_x2<<<dim3(30, 32), 256, 0, stream>>>(x_hi, wqt_hi, wqt_lo, b_qkv,
                                               qf, kf, vf, 4096, 3840, 1280);
  rope_pack_kernel<<<dim3(64, 16), 256, 0, stream>>>(qf, kf, cs, sn, khi, klo);
  vt_pack_kernel<<<dim3(64, 16), 256, 0, stream>>>(vf, vthi, vtlo);
  sched_kernel<<<1, 64, 0, stream>>>(cu, perm);
  attn_kernel<<<1024, 128, 0, stream>>>(qf, khi, klo, vthi, vtlo, cu, o_hi, perm);
  gemm128_x2<<<dim3(10, 32), 256, 0, stream>>>(o_hi, wpt_hi, wpt_lo, b_proj,
                                               out, nullptr, nullptr, 4096, 1280, 1280);
}